// Round 1
// baseline (750.462 us; speedup 1.0000x reference)
//
#include <hip/hip_runtime.h>
#include <math.h>

#define DD 128  // embed dim, fixed by problem

// ---------------- K0: zero hist ----------------
__global__ void k_zero(int* p, int n) {
    int i = blockIdx.x * blockDim.x + threadIdx.x;
    if (i < n) p[i] = 0;
}

// ---------------- K1: precompute M = Wq Wk^T, t = Wk bq, u = Wq bk, s0 = bq.bk ----
// grid 128 blocks x 128 threads; block dp computes M[dp][:]
__global__ void k_precompute(const float* __restrict__ Wq, const float* __restrict__ bq,
                             const float* __restrict__ Wk, const float* __restrict__ bk,
                             float* __restrict__ M, float* __restrict__ tvec,
                             float* __restrict__ uvec, float* __restrict__ s0) {
    __shared__ float wkT[64][129];   // [p-chunk][d], padded
    __shared__ float wqrow[128];
    __shared__ float bqs[128];
    const int dp  = blockIdx.x;
    const int tid = threadIdx.x;
    wqrow[tid] = Wq[dp * DD + tid];
    bqs[tid]   = bq[tid];
    float acc = 0.f, tacc = 0.f;
    for (int ch = 0; ch < 2; ++ch) {
        __syncthreads();
        // load Wk[d][ch*64 + j] -> wkT[j][d]
        for (int i = tid; i < 128 * 64; i += 128) {
            int d = i >> 6, j = i & 63;
            wkT[j][d] = Wk[d * DD + ch * 64 + j];
        }
        __syncthreads();
        #pragma unroll 8
        for (int j = 0; j < 64; ++j) {
            float w = wkT[j][tid];            // Wk[tid][p], p = ch*64+j
            acc  += wqrow[ch * 64 + j] * w;   // M[dp][tid]
            tacc += bqs[ch * 64 + j] * w;     // t[tid]
        }
    }
    M[dp * DD + tid] = acc;
    if (dp == 0) {
        tvec[tid] = tacc;
        float ua = 0.f;
        for (int p = 0; p < DD; ++p) ua += Wq[tid * DD + p] * bk[p];
        uvec[tid] = ua;
        if (tid == 0) {
            float s = 0.f;
            for (int p = 0; p < DD; ++p) s += bq[p] * bk[p];
            *s0 = s;
        }
    }
}

// ---------------- K2: zs[q][d] = scale*( sum_d' queries[q][d'] M[d'][d] + t[d] ) ----
// block 256 threads covers 64 queries x 128 d; thread tile 4q x 8d
__global__ __launch_bounds__(256) void k_gemm(const float* __restrict__ queries,
                                              const float* __restrict__ M,
                                              const float* __restrict__ tvec,
                                              float* __restrict__ zs, int Q, float scale) {
    __shared__ __align__(16) float Ms[32 * 128];  // 16 KB   [k][d]
    __shared__ float qs[64 * 33];                 // 8.4 KB  [q][k] padded
    const int t  = threadIdx.x;
    const int tx = t & 15;       // d-tile: d0 = tx*8
    const int ty = t >> 4;       // q-tile: q0 = ty*4
    const int qbase = blockIdx.x * 64;
    float acc[4][8];
    #pragma unroll
    for (int j = 0; j < 4; ++j)
        #pragma unroll
        for (int i = 0; i < 8; ++i) acc[j][i] = 0.f;

    for (int kc = 0; kc < 4; ++kc) {
        __syncthreads();
        // stage M chunk: rows kc*32..+31, all 128 cols (float4)
        for (int i = t; i < 1024; i += 256) {
            int r = i >> 5, c4 = i & 31;
            ((float4*)Ms)[r * 32 + c4] = ((const float4*)(M + (size_t)(kc * 32 + r) * DD))[c4];
        }
        // stage queries chunk: 64 rows x 32 k (scalar, padded stride 33)
        for (int i = t; i < 2048; i += 256) {
            int r = i >> 5, c = i & 31;
            int q = qbase + r;
            qs[r * 33 + c] = (q < Q) ? queries[(size_t)q * DD + kc * 32 + c] : 0.f;
        }
        __syncthreads();
        #pragma unroll 8
        for (int k = 0; k < 32; ++k) {
            float4 ma = *(const float4*)&Ms[k * 128 + tx * 8];
            float4 mb = *(const float4*)&Ms[k * 128 + tx * 8 + 4];
            float mv[8] = {ma.x, ma.y, ma.z, ma.w, mb.x, mb.y, mb.z, mb.w};
            #pragma unroll
            for (int j = 0; j < 4; ++j) {
                float qv = qs[(ty * 4 + j) * 33 + k];
                #pragma unroll
                for (int i = 0; i < 8; ++i) acc[j][i] = fmaf(qv, mv[i], acc[j][i]);
            }
        }
    }
    float4 t0 = *(const float4*)(tvec + tx * 8);
    float4 t1 = *(const float4*)(tvec + tx * 8 + 4);
    float tv[8] = {t0.x, t0.y, t0.z, t0.w, t1.x, t1.y, t1.z, t1.w};
    #pragma unroll
    for (int j = 0; j < 4; ++j) {
        int q = qbase + ty * 4 + j;
        if (q < Q) {
            float o[8];
            #pragma unroll
            for (int i = 0; i < 8; ++i) o[i] = (acc[j][i] + tv[i]) * scale;
            float4 w0 = {o[0], o[1], o[2], o[3]};
            float4 w1 = {o[4], o[5], o[6], o[7]};
            *(float4*)(zs + (size_t)q * DD + tx * 8)     = w0;
            *(float4*)(zs + (size_t)q * DD + tx * 8 + 4) = w1;
        }
    }
}

// ---------------- K3: histogram ----------------
__global__ void k_hist(const int* __restrict__ idx, int* __restrict__ hist, int E) {
    int i = blockIdx.x * blockDim.x + threadIdx.x;
    if (i < E) atomicAdd(&hist[idx[i]], 1);
}

// ---------------- K4a: per-block sums ----------------
__global__ void k_scan1(const int* __restrict__ hist, int* __restrict__ bsum, int Q) {
    int i = blockIdx.x * 256 + threadIdx.x;
    int v = (i < Q) ? hist[i] : 0;
    #pragma unroll
    for (int off = 1; off < 64; off <<= 1) v += __shfl_xor(v, off);
    __shared__ int sd[4];
    if ((threadIdx.x & 63) == 0) sd[threadIdx.x >> 6] = v;
    __syncthreads();
    if (threadIdx.x == 0) bsum[blockIdx.x] = sd[0] + sd[1] + sd[2] + sd[3];
}

// ---------------- K4b: scan of block sums (1 block, NB<=256) ----------------
__global__ void k_scan2(const int* __restrict__ bsum, int* __restrict__ boff, int NB) {
    __shared__ int s[256];
    int t = threadIdx.x;
    int v = (t < NB) ? bsum[t] : 0;
    s[t] = v;
    __syncthreads();
    for (int off = 1; off < 256; off <<= 1) {
        int add = (t >= off) ? s[t - off] : 0;
        __syncthreads();
        s[t] += add;
        __syncthreads();
    }
    if (t < NB) boff[t] = s[t] - v;  // exclusive
}

// ---------------- K4c: final exclusive scan -> seg_start, cursor ----------------
__global__ void k_scan3(const int* __restrict__ hist, const int* __restrict__ boff,
                        int* __restrict__ seg_start, int* __restrict__ cursor, int Q) {
    __shared__ int s[256];
    int t = threadIdx.x;
    int i = blockIdx.x * 256 + t;
    int v = (i < Q) ? hist[i] : 0;
    s[t] = v;
    __syncthreads();
    for (int off = 1; off < 256; off <<= 1) {
        int add = (t >= off) ? s[t - off] : 0;
        __syncthreads();
        s[t] += add;
        __syncthreads();
    }
    if (i < Q) {
        int excl = s[t] - v + boff[blockIdx.x];
        seg_start[i] = excl;
        cursor[i]    = excl;
    }
}

// ---------------- K5: scatter -> perm ----------------
__global__ void k_scatter(const int* __restrict__ idx, int* __restrict__ cursor,
                          int* __restrict__ perm, int E) {
    int i = blockIdx.x * blockDim.x + threadIdx.x;
    if (i < E) {
        int q   = idx[i];
        int pos = atomicAdd(&cursor[q], 1);
        perm[pos] = i;
    }
}

// ---------------- K6: fused per-segment softmax + weighted sum ----------------
// block 256 = 4 waves; wave w owns segment q = blockIdx*4 + w
// zs lives in the d_out attn region; each wave reads zs[q] then overwrites with attn[q]
#define EXCAP 512
__global__ __launch_bounds__(256) void k_attn(const float* __restrict__ SV,
                                              const float* __restrict__ queries,
                                              const float* __restrict__ uvec,
                                              const float* __restrict__ s0ptr,
                                              const int* __restrict__ hist,
                                              const int* __restrict__ seg_start,
                                              const int* __restrict__ perm,
                                              float* __restrict__ zs_attn,  // [Q][128] in d_out
                                              float* __restrict__ scores,   // [E] in d_out
                                              int Q, float scale) {
    __shared__ float exbuf[4][EXCAP];
    const int wid  = threadIdx.x >> 6;
    const int lane = threadIdx.x & 63;
    const int q    = blockIdx.x * 4 + wid;
    const bool act = (q < Q);

    float2 zv = make_float2(0.f, 0.f), qv2 = zv, uv2 = zv;
    int cnt = 0, start = 0;
    if (act) {
        zv    = ((const float2*)(zs_attn + (size_t)q * DD))[lane];
        qv2   = ((const float2*)(queries + (size_t)q * DD))[lane];
        uv2   = ((const float2*)uvec)[lane];
        cnt   = hist[q];
        start = seg_start[q];
    }
    // cq = scale*(queries[q].u + s0)
    float cd = qv2.x * uv2.x + qv2.y * uv2.y;
    #pragma unroll
    for (int off = 1; off < 64; off <<= 1) cd += __shfl_xor(cd, off);
    float cq = (cd + s0ptr[0]) * scale;

    float accx = 0.f, accy = 0.f, ssum = 0.f;
    for (int base = 0; base < cnt; base += 64) {
        int m  = min(64, cnt - base);
        int pe = (lane < m) ? perm[start + base + lane] : 0;
        int e0 = __shfl(pe, 0);
        float2 sv = ((const float2*)(SV + (size_t)e0 * DD))[lane];
        for (int i = 0; i < m; ++i) {
            float2 svn = make_float2(0.f, 0.f);
            if (i + 1 < m) {
                int en = __shfl(pe, i + 1);
                svn = ((const float2*)(SV + (size_t)en * DD))[lane];
            }
            float p = fmaf(sv.x, zv.x, sv.y * zv.y);
            #pragma unroll
            for (int off = 1; off < 64; off <<= 1) p += __shfl_xor(p, off);
            float ex = __expf(p + cq);
            ssum += ex;
            accx = fmaf(ex, sv.x, accx);
            accy = fmaf(ex, sv.y, accy);
            if (lane == 0 && (base + i) < EXCAP) exbuf[wid][base + i] = ex;
            sv = svn;
        }
    }
    __syncthreads();  // uniform per block? loops are wave-uniform; all threads reach here
    if (act) {
        float2* arow = (float2*)(zs_attn + (size_t)q * DD);
        if (cnt == 0) {
            arow[lane] = make_float2(0.f, 0.f);
        } else {
            float inv = 1.f / ssum;
            arow[lane] = make_float2(accx * inv, accy * inv);
            int lim = min(cnt, EXCAP);
            for (int i = lane; i < lim; i += 64)
                scores[perm[start + i]] = exbuf[wid][i] * inv;
        }
    }
}

extern "C" void kernel_launch(void* const* d_in, const int* in_sizes, int n_in,
                              void* d_out, int out_size, void* d_ws, size_t ws_size,
                              hipStream_t stream) {
    const float* SV      = (const float*)d_in[0];
    const int*   indices = (const int*)d_in[1];
    const float* queries = (const float*)d_in[2];
    const float* Wq      = (const float*)d_in[3];
    const float* bq      = (const float*)d_in[4];
    const float* Wk      = (const float*)d_in[5];
    const float* bk      = (const float*)d_in[6];

    const int E = in_sizes[1];
    const int Q = in_sizes[2] / DD;
    const float scale = 1.0f / sqrtf((float)DD);

    // d_out layout: scores [E] then attn [Q*128] (zs staged in attn region)
    float* scores  = (float*)d_out;
    float* zs_attn = (float*)d_out + E;

    // workspace layout (4-byte units)
    float* ws   = (float*)d_ws;
    float* M    = ws;                 // 16384
    float* tvec = ws + 16384;         // 128
    float* uvec = ws + 16512;         // 128
    float* s0   = ws + 16640;         // 1 (pad to 16896)
    int* hist      = (int*)ws + 16896;
    int* seg_start = hist + Q;
    int* cursor    = seg_start + Q;
    int* bsum      = cursor + Q;      // 256
    int* boff      = bsum + 256;      // 256
    int* perm      = boff + 256;      // E

    const int NB = (Q + 255) / 256;   // scan blocks (<=256 assumed; Q=50k -> 196)

    hipLaunchKernelGGL(k_zero, dim3(NB), dim3(256), 0, stream, hist, Q);
    hipLaunchKernelGGL(k_precompute, dim3(128), dim3(128), 0, stream,
                       Wq, bq, Wk, bk, M, tvec, uvec, s0);
    hipLaunchKernelGGL(k_gemm, dim3((Q + 63) / 64), dim3(256), 0, stream,
                       queries, M, tvec, zs_attn, Q, scale);
    hipLaunchKernelGGL(k_hist, dim3((E + 255) / 256), dim3(256), 0, stream,
                       indices, hist, E);
    hipLaunchKernelGGL(k_scan1, dim3(NB), dim3(256), 0, stream, hist, bsum, Q);
    hipLaunchKernelGGL(k_scan2, dim3(1), dim3(256), 0, stream, bsum, boff, NB);
    hipLaunchKernelGGL(k_scan3, dim3(NB), dim3(256), 0, stream,
                       hist, boff, seg_start, cursor, Q);
    hipLaunchKernelGGL(k_scatter, dim3((E + 255) / 256), dim3(256), 0, stream,
                       indices, cursor, perm, E);
    hipLaunchKernelGGL(k_attn, dim3((Q + 3) / 4), dim3(256), 0, stream,
                       SV, queries, uvec, s0, hist, seg_start, perm,
                       zs_attn, scores, Q, scale);
}

// Round 2
// 737.124 us; speedup vs baseline: 1.0181x; 1.0181x over previous
//
#include <hip/hip_runtime.h>
#include <math.h>

#define DD 128  // embed dim, fixed by problem

// ---------------- K_init: zero hist+done (blocks 0..NB-1) and precompute
//   M = Wq Wk^T, t = Wk bq, u = Wq bk, s0 = bq.bk (blocks NB..NB+127)
// 128 threads per block.
__global__ void k_init(const float* __restrict__ Wq, const float* __restrict__ bq,
                       const float* __restrict__ Wk, const float* __restrict__ bk,
                       float* __restrict__ M, float* __restrict__ tvec,
                       float* __restrict__ uvec, float* __restrict__ s0,
                       int* __restrict__ hist, int* __restrict__ done,
                       int Q, int NB) {
    const int tid = threadIdx.x;
    if (blockIdx.x < (unsigned)NB) {
        // zero 256 hist entries per block with 128 threads
        int base = blockIdx.x * 256;
        for (int j = base + tid; j < base + 256; j += 128)
            if (j < Q) hist[j] = 0;
        if (blockIdx.x == 0 && tid == 0) *done = 0;
        return;
    }
    // ---- precompute role ----
    __shared__ float wkT[64][129];   // [p-chunk][d], padded
    __shared__ float wqrow[128];
    __shared__ float bqs[128];
    const int dp = blockIdx.x - NB;
    wqrow[tid] = Wq[dp * DD + tid];
    bqs[tid]   = bq[tid];
    float acc = 0.f, tacc = 0.f;
    for (int ch = 0; ch < 2; ++ch) {
        __syncthreads();
        for (int i = tid; i < 128 * 64; i += 128) {
            int d = i >> 6, j = i & 63;
            wkT[j][d] = Wk[d * DD + ch * 64 + j];
        }
        __syncthreads();
        #pragma unroll 8
        for (int j = 0; j < 64; ++j) {
            float w = wkT[j][tid];            // Wk[tid][p], p = ch*64+j
            acc  += wqrow[ch * 64 + j] * w;   // M[dp][tid]
            tacc += bqs[ch * 64 + j] * w;     // t[tid]
        }
    }
    M[dp * DD + tid] = acc;
    if (dp == 0) {
        tvec[tid] = tacc;
        float ua = 0.f;
        for (int p = 0; p < DD; ++p) ua += Wq[tid * DD + p] * bk[p];
        uvec[tid] = ua;
        if (tid == 0) {
            float s = 0.f;
            for (int p = 0; p < DD; ++p) s += bq[p] * bk[p];
            *s0 = s;
        }
    }
}

// ---------------- K_gemm: zs[q][d] = scale*( sum_d' queries[q][d'] M[d'][d] + t[d] )
__global__ __launch_bounds__(256) void k_gemm(const float* __restrict__ queries,
                                              const float* __restrict__ M,
                                              const float* __restrict__ tvec,
                                              float* __restrict__ zs, int Q, float scale) {
    __shared__ __align__(16) float Ms[32 * 128];  // [k][d]
    __shared__ float qs[64 * 33];                 // [q][k] padded
    const int t  = threadIdx.x;
    const int tx = t & 15;       // d-tile: d0 = tx*8
    const int ty = t >> 4;       // q-tile: q0 = ty*4
    const int qbase = blockIdx.x * 64;
    float acc[4][8];
    #pragma unroll
    for (int j = 0; j < 4; ++j)
        #pragma unroll
        for (int i = 0; i < 8; ++i) acc[j][i] = 0.f;

    for (int kc = 0; kc < 4; ++kc) {
        __syncthreads();
        for (int i = t; i < 1024; i += 256) {
            int r = i >> 5, c4 = i & 31;
            ((float4*)Ms)[r * 32 + c4] = ((const float4*)(M + (size_t)(kc * 32 + r) * DD))[c4];
        }
        for (int i = t; i < 2048; i += 256) {
            int r = i >> 5, c = i & 31;
            int q = qbase + r;
            qs[r * 33 + c] = (q < Q) ? queries[(size_t)q * DD + kc * 32 + c] : 0.f;
        }
        __syncthreads();
        #pragma unroll 8
        for (int k = 0; k < 32; ++k) {
            float4 ma = *(const float4*)&Ms[k * 128 + tx * 8];
            float4 mb = *(const float4*)&Ms[k * 128 + tx * 8 + 4];
            float mv[8] = {ma.x, ma.y, ma.z, ma.w, mb.x, mb.y, mb.z, mb.w};
            #pragma unroll
            for (int j = 0; j < 4; ++j) {
                float qv = qs[(ty * 4 + j) * 33 + k];
                #pragma unroll
                for (int i = 0; i < 8; ++i) acc[j][i] = fmaf(qv, mv[i], acc[j][i]);
            }
        }
    }
    float4 t0 = *(const float4*)(tvec + tx * 8);
    float4 t1 = *(const float4*)(tvec + tx * 8 + 4);
    float tv[8] = {t0.x, t0.y, t0.z, t0.w, t1.x, t1.y, t1.z, t1.w};
    #pragma unroll
    for (int j = 0; j < 4; ++j) {
        int q = qbase + ty * 4 + j;
        if (q < Q) {
            float o[8];
            #pragma unroll
            for (int i = 0; i < 8; ++i) o[i] = (acc[j][i] + tv[i]) * scale;
            float4 w0 = {o[0], o[1], o[2], o[3]};
            float4 w1 = {o[4], o[5], o[6], o[7]};
            *(float4*)(zs + (size_t)q * DD + tx * 8)     = w0;
            *(float4*)(zs + (size_t)q * DD + tx * 8 + 4) = w1;
        }
    }
}

// ---------------- K_hist ----------------
__global__ void k_hist(const int* __restrict__ idx, int* __restrict__ hist, int E) {
    int i = blockIdx.x * blockDim.x + threadIdx.x;
    if (i < E) atomicAdd(&hist[idx[i]], 1);
}

// ---------------- K_scan12: per-block sums + last-block scans bsum -> boff ----
__global__ void k_scan12(const int* __restrict__ hist, int* __restrict__ bsum,
                         int* __restrict__ boff, int* __restrict__ done,
                         int Q, int NB) {
    const int t = threadIdx.x;
    int i = blockIdx.x * 256 + t;
    int v = (i < Q) ? hist[i] : 0;
    #pragma unroll
    for (int off = 1; off < 64; off <<= 1) v += __shfl_xor(v, off);
    __shared__ int sd[4];
    __shared__ int ticket;
    if ((t & 63) == 0) sd[t >> 6] = v;
    __syncthreads();
    if (t == 0) {
        bsum[blockIdx.x] = sd[0] + sd[1] + sd[2] + sd[3];
        __threadfence();                      // release bsum write
        ticket = atomicAdd(done, 1);
    }
    __syncthreads();
    if (ticket == NB - 1) {                   // last block does the bsum scan
        __threadfence();                      // acquire all bsum writes
        __shared__ int s[256];
        int vv = (t < NB) ? bsum[t] : 0;
        s[t] = vv;
        __syncthreads();
        for (int off = 1; off < 256; off <<= 1) {
            int add = (t >= off) ? s[t - off] : 0;
            __syncthreads();
            s[t] += add;
            __syncthreads();
        }
        if (t < NB) boff[t] = s[t] - vv;      // exclusive
    }
}

// ---------------- K_scan3: final exclusive scan -> seg_start, cursor ----------
__global__ void k_scan3(const int* __restrict__ hist, const int* __restrict__ boff,
                        int* __restrict__ seg_start, int* __restrict__ cursor, int Q) {
    __shared__ int s[256];
    int t = threadIdx.x;
    int i = blockIdx.x * 256 + t;
    int v = (i < Q) ? hist[i] : 0;
    s[t] = v;
    __syncthreads();
    for (int off = 1; off < 256; off <<= 1) {
        int add = (t >= off) ? s[t - off] : 0;
        __syncthreads();
        s[t] += add;
        __syncthreads();
    }
    if (i < Q) {
        int excl = s[t] - v + boff[blockIdx.x];
        seg_start[i] = excl;
        cursor[i]    = excl;
    }
}

// ---------------- K_scatter -> perm ----------------
__global__ void k_scatter(const int* __restrict__ idx, int* __restrict__ cursor,
                          int* __restrict__ perm, int E) {
    int i = blockIdx.x * blockDim.x + threadIdx.x;
    if (i < E) {
        int q   = idx[i];
        int pos = atomicAdd(&cursor[q], 1);
        perm[pos] = i;
    }
}

// ---------------- K_attn: fused per-segment softmax + weighted sum, 4-wide ----
// block 256 = 4 waves; wave w owns segment q = blockIdx*4 + w. No LDS, no barriers.
// Writes UNNORMALIZED ex into scores[]; k_rescale applies 1/sum afterwards.
__global__ __launch_bounds__(256) void k_attn(const float* __restrict__ SV,
                                              const float* __restrict__ queries,
                                              const float* __restrict__ uvec,
                                              const float* __restrict__ s0ptr,
                                              const int* __restrict__ hist,
                                              const int* __restrict__ seg_start,
                                              const int* __restrict__ perm,
                                              float* __restrict__ zs_attn,  // [Q][128] in d_out
                                              float* __restrict__ scores,   // [E] in d_out (raw ex)
                                              float* __restrict__ invsum,   // [Q] in ws
                                              int Q, float scale) {
    const int wid  = threadIdx.x >> 6;
    const int lane = threadIdx.x & 63;
    const int q    = blockIdx.x * 4 + wid;
    if (q >= Q) return;

    float2 zv  = ((const float2*)(zs_attn + (size_t)q * DD))[lane];
    float2 qv2 = ((const float2*)(queries + (size_t)q * DD))[lane];
    float2 uv2 = ((const float2*)uvec)[lane];
    // cq = scale*(queries[q].u + s0)
    float cd = fmaf(qv2.x, uv2.x, qv2.y * uv2.y);
    #pragma unroll
    for (int off = 1; off < 64; off <<= 1) cd += __shfl_xor(cd, off);
    const float cq = (cd + s0ptr[0]) * scale;

    const int cnt   = hist[q];
    const int start = seg_start[q];

    float accx = 0.f, accy = 0.f, ssum = 0.f;
    for (int base = 0; base < cnt; base += 64) {
        const int m = min(64, cnt - base);
        int pe = perm[start + base + ((lane < m) ? lane : 0)];
        for (int i = 0; i < m; i += 4) {
            // clamp duplicate indices for the ragged tail (masked below)
            const int i1 = min(i + 1, m - 1);
            const int i2 = min(i + 2, m - 1);
            const int i3 = min(i + 3, m - 1);
            const int e0 = __shfl(pe, i);
            const int e1 = __shfl(pe, i1);
            const int e2 = __shfl(pe, i2);
            const int e3 = __shfl(pe, i3);
            // 4 independent gathered row loads -> 4x MLP
            const float2 s0v = ((const float2*)(SV + (size_t)e0 * DD))[lane];
            const float2 s1v = ((const float2*)(SV + (size_t)e1 * DD))[lane];
            const float2 s2v = ((const float2*)(SV + (size_t)e2 * DD))[lane];
            const float2 s3v = ((const float2*)(SV + (size_t)e3 * DD))[lane];
            float p0 = fmaf(s0v.x, zv.x, s0v.y * zv.y);
            float p1 = fmaf(s1v.x, zv.x, s1v.y * zv.y);
            float p2 = fmaf(s2v.x, zv.x, s2v.y * zv.y);
            float p3 = fmaf(s3v.x, zv.x, s3v.y * zv.y);
            // 4 interleaved butterfly reduces (independent chains pipeline)
            #pragma unroll
            for (int off = 1; off < 64; off <<= 1) {
                p0 += __shfl_xor(p0, off);
                p1 += __shfl_xor(p1, off);
                p2 += __shfl_xor(p2, off);
                p3 += __shfl_xor(p3, off);
            }
            const float ex0 = __expf(p0 + cq);
            const float ex1 = (i + 1 < m) ? __expf(p1 + cq) : 0.f;
            const float ex2 = (i + 2 < m) ? __expf(p2 + cq) : 0.f;
            const float ex3 = (i + 3 < m) ? __expf(p3 + cq) : 0.f;
            ssum += (ex0 + ex1) + (ex2 + ex3);
            accx = fmaf(ex0, s0v.x, fmaf(ex1, s1v.x, fmaf(ex2, s2v.x, fmaf(ex3, s3v.x, accx))));
            accy = fmaf(ex0, s0v.y, fmaf(ex1, s1v.y, fmaf(ex2, s2v.y, fmaf(ex3, s3v.y, accy))));
            if (lane == 0) {
                scores[e0] = ex0;
                if (i + 1 < m) scores[e1] = ex1;
                if (i + 2 < m) scores[e2] = ex2;
                if (i + 3 < m) scores[e3] = ex3;
            }
        }
    }

    float2* arow = (float2*)(zs_attn + (size_t)q * DD);
    if (cnt == 0) {
        arow[lane] = make_float2(0.f, 0.f);
    } else {
        const float inv = 1.f / ssum;
        arow[lane] = make_float2(accx * inv, accy * inv);
        if (lane == 0) invsum[q] = inv;
    }
}

// ---------------- K_rescale: scores[e] = ex[e] * invsum[idx[e]] ----------------
__global__ void k_rescale(const int* __restrict__ idx, const float* __restrict__ invsum,
                          float* __restrict__ scores, int E) {
    int i = blockIdx.x * blockDim.x + threadIdx.x;
    if (i < E) scores[i] = scores[i] * invsum[idx[i]];
}

extern "C" void kernel_launch(void* const* d_in, const int* in_sizes, int n_in,
                              void* d_out, int out_size, void* d_ws, size_t ws_size,
                              hipStream_t stream) {
    const float* SV      = (const float*)d_in[0];
    const int*   indices = (const int*)d_in[1];
    const float* queries = (const float*)d_in[2];
    const float* Wq      = (const float*)d_in[3];
    const float* bq      = (const float*)d_in[4];
    const float* Wk      = (const float*)d_in[5];
    const float* bk      = (const float*)d_in[6];

    const int E = in_sizes[1];
    const int Q = in_sizes[2] / DD;
    const float scale = 1.0f / sqrtf((float)DD);

    // d_out layout: scores [E] then attn [Q*128] (zs staged in attn region)
    float* scores  = (float*)d_out;
    float* zs_attn = (float*)d_out + E;

    // workspace layout (4-byte units)
    float* ws   = (float*)d_ws;
    float* M    = ws;                 // 16384
    float* tvec = ws + 16384;         // 128
    float* uvec = ws + 16512;         // 128
    float* s0   = ws + 16640;         // 1 (pad to 17024)
    int* hist      = (int*)ws + 17024;
    int* seg_start = hist + Q;
    int* cursor    = seg_start + Q;
    int* bsum      = cursor + Q;      // 256
    int* boff      = bsum + 256;      // 256
    int* done      = boff + 256;      // 1 (pad 64)
    int* perm      = done + 64;       // E
    float* invsum  = (float*)(perm + E);  // Q

    const int NB = (Q + 255) / 256;   // scan blocks (Q=50k -> 196, <=256)

    hipLaunchKernelGGL(k_init, dim3(NB + 128), dim3(128), 0, stream,
                       Wq, bq, Wk, bk, M, tvec, uvec, s0, hist, done, Q, NB);
    hipLaunchKernelGGL(k_gemm, dim3((Q + 63) / 64), dim3(256), 0, stream,
                       queries, M, tvec, zs_attn, Q, scale);
    hipLaunchKernelGGL(k_hist, dim3((E + 255) / 256), dim3(256), 0, stream,
                       indices, hist, E);
    hipLaunchKernelGGL(k_scan12, dim3(NB), dim3(256), 0, stream,
                       hist, bsum, boff, done, Q, NB);
    hipLaunchKernelGGL(k_scan3, dim3(NB), dim3(256), 0, stream,
                       hist, boff, seg_start, cursor, Q);
    hipLaunchKernelGGL(k_scatter, dim3((E + 255) / 256), dim3(256), 0, stream,
                       indices, cursor, perm, E);
    hipLaunchKernelGGL(k_attn, dim3((Q + 3) / 4), dim3(256), 0, stream,
                       SV, queries, uvec, s0, hist, seg_start, perm,
                       zs_attn, scores, invsum, Q, scale);
    hipLaunchKernelGGL(k_rescale, dim3((E + 255) / 256), dim3(256), 0, stream,
                       indices, invsum, scores, E);
}

// Round 3
// 717.351 us; speedup vs baseline: 1.0462x; 1.0276x over previous
//
#include <hip/hip_runtime.h>
#include <math.h>

#define DD 128  // embed dim, fixed by problem

// ---------------- K_init: zero hist+done (blocks 0..NB-1) and precompute
//   M = Wq Wk^T, t = Wk bq, u = Wq bk, s0 = bq.bk (blocks NB..NB+127)
__global__ void k_init(const float* __restrict__ Wq, const float* __restrict__ bq,
                       const float* __restrict__ Wk, const float* __restrict__ bk,
                       float* __restrict__ M, float* __restrict__ tvec,
                       float* __restrict__ uvec, float* __restrict__ s0,
                       int* __restrict__ hist, int* __restrict__ done,
                       int Q, int NB) {
    const int tid = threadIdx.x;
    if (blockIdx.x < (unsigned)NB) {
        int base = blockIdx.x * 256;
        for (int j = base + tid; j < base + 256; j += 128)
            if (j < Q) hist[j] = 0;
        if (blockIdx.x == 0 && tid == 0) *done = 0;
        return;
    }
    __shared__ float wkT[64][129];   // [p-chunk][d], padded
    __shared__ float wqrow[128];
    __shared__ float bqs[128];
    const int dp = blockIdx.x - NB;
    wqrow[tid] = Wq[dp * DD + tid];
    bqs[tid]   = bq[tid];
    float acc = 0.f, tacc = 0.f;
    for (int ch = 0; ch < 2; ++ch) {
        __syncthreads();
        for (int i = tid; i < 128 * 64; i += 128) {
            int d = i >> 6, j = i & 63;
            wkT[j][d] = Wk[d * DD + ch * 64 + j];
        }
        __syncthreads();
        #pragma unroll 8
        for (int j = 0; j < 64; ++j) {
            float w = wkT[j][tid];            // Wk[tid][p], p = ch*64+j
            acc  += wqrow[ch * 64 + j] * w;   // M[dp][tid]
            tacc += bqs[ch * 64 + j] * w;     // t[tid]
        }
    }
    M[dp * DD + tid] = acc;
    if (dp == 0) {
        tvec[tid] = tacc;
        float ua = 0.f;
        for (int p = 0; p < DD; ++p) ua += Wq[tid * DD + p] * bk[p];
        uvec[tid] = ua;
        if (tid == 0) {
            float s = 0.f;
            for (int p = 0; p < DD; ++p) s += bq[p] * bk[p];
            *s0 = s;
        }
    }
}

// ---------------- K_gemm_hist: fused independent stages ----------------
// blocks [0,GB): zs[q][d] = scale*( queries[q,:] M[:,d] + t[d] )
// blocks [GB,GB+HB): histogram of indices
__global__ __launch_bounds__(256) void k_gemm_hist(const float* __restrict__ queries,
                                                   const float* __restrict__ M,
                                                   const float* __restrict__ tvec,
                                                   float* __restrict__ zs, int Q, float scale,
                                                   const int* __restrict__ idx,
                                                   int* __restrict__ hist, int E, int GB) {
    if (blockIdx.x >= (unsigned)GB) {
        int i = (blockIdx.x - GB) * 256 + threadIdx.x;
        if (i < E) atomicAdd(&hist[idx[i]], 1);
        return;
    }
    __shared__ __align__(16) float Ms[32 * 128];  // [k][d]
    __shared__ float qs[64 * 33];                 // [q][k] padded
    const int t  = threadIdx.x;
    const int tx = t & 15;       // d-tile: d0 = tx*8
    const int ty = t >> 4;       // q-tile: q0 = ty*4
    const int qbase = blockIdx.x * 64;
    float acc[4][8];
    #pragma unroll
    for (int j = 0; j < 4; ++j)
        #pragma unroll
        for (int i = 0; i < 8; ++i) acc[j][i] = 0.f;

    for (int kc = 0; kc < 4; ++kc) {
        __syncthreads();
        for (int i = t; i < 1024; i += 256) {
            int r = i >> 5, c4 = i & 31;
            ((float4*)Ms)[r * 32 + c4] = ((const float4*)(M + (size_t)(kc * 32 + r) * DD))[c4];
        }
        for (int i = t; i < 2048; i += 256) {
            int r = i >> 5, c = i & 31;
            int q = qbase + r;
            qs[r * 33 + c] = (q < Q) ? queries[(size_t)q * DD + kc * 32 + c] : 0.f;
        }
        __syncthreads();
        #pragma unroll 8
        for (int k = 0; k < 32; ++k) {
            float4 ma = *(const float4*)&Ms[k * 128 + tx * 8];
            float4 mb = *(const float4*)&Ms[k * 128 + tx * 8 + 4];
            float mv[8] = {ma.x, ma.y, ma.z, ma.w, mb.x, mb.y, mb.z, mb.w};
            #pragma unroll
            for (int j = 0; j < 4; ++j) {
                float qv = qs[(ty * 4 + j) * 33 + k];
                #pragma unroll
                for (int i = 0; i < 8; ++i) acc[j][i] = fmaf(qv, mv[i], acc[j][i]);
            }
        }
    }
    float4 t0 = *(const float4*)(tvec + tx * 8);
    float4 t1 = *(const float4*)(tvec + tx * 8 + 4);
    float tv[8] = {t0.x, t0.y, t0.z, t0.w, t1.x, t1.y, t1.z, t1.w};
    #pragma unroll
    for (int j = 0; j < 4; ++j) {
        int q = qbase + ty * 4 + j;
        if (q < Q) {
            float o[8];
            #pragma unroll
            for (int i = 0; i < 8; ++i) o[i] = (acc[j][i] + tv[i]) * scale;
            float4 w0 = {o[0], o[1], o[2], o[3]};
            float4 w1 = {o[4], o[5], o[6], o[7]};
            *(float4*)(zs + (size_t)q * DD + tx * 8)     = w0;
            *(float4*)(zs + (size_t)q * DD + tx * 8 + 4) = w1;
        }
    }
}

// ---------------- K_scan12: per-block sums + last-block scans bsum -> boff ----
__global__ void k_scan12(const int* __restrict__ hist, int* __restrict__ bsum,
                         int* __restrict__ boff, int* __restrict__ done,
                         int Q, int NB) {
    const int t = threadIdx.x;
    int i = blockIdx.x * 256 + t;
    int v = (i < Q) ? hist[i] : 0;
    #pragma unroll
    for (int off = 1; off < 64; off <<= 1) v += __shfl_xor(v, off);
    __shared__ int sd[4];
    __shared__ int ticket;
    if ((t & 63) == 0) sd[t >> 6] = v;
    __syncthreads();
    if (t == 0) {
        bsum[blockIdx.x] = sd[0] + sd[1] + sd[2] + sd[3];
        __threadfence();                      // release bsum write
        ticket = atomicAdd(done, 1);
    }
    __syncthreads();
    if (ticket == NB - 1) {                   // last block scans bsum
        __threadfence();                      // acquire all bsum writes
        __shared__ int s[256];
        int vv = (t < NB) ? bsum[t] : 0;
        s[t] = vv;
        __syncthreads();
        for (int off = 1; off < 256; off <<= 1) {
            int add = (t >= off) ? s[t - off] : 0;
            __syncthreads();
            s[t] += add;
            __syncthreads();
        }
        if (t < NB) boff[t] = s[t] - vv;      // exclusive
    }
}

// ---------------- K_scan3: final exclusive scan -> seg_start, cursor ----------
__global__ void k_scan3(const int* __restrict__ hist, const int* __restrict__ boff,
                        int* __restrict__ seg_start, int* __restrict__ cursor, int Q) {
    __shared__ int s[256];
    int t = threadIdx.x;
    int i = blockIdx.x * 256 + t;
    int v = (i < Q) ? hist[i] : 0;
    s[t] = v;
    __syncthreads();
    for (int off = 1; off < 256; off <<= 1) {
        int add = (t >= off) ? s[t - off] : 0;
        __syncthreads();
        s[t] += add;
        __syncthreads();
    }
    if (i < Q) {
        int excl = s[t] - v + boff[blockIdx.x];
        seg_start[i] = excl;
        cursor[i]    = excl;
    }
}

// ---------------- K_scatter -> perm + inv_pos ----------------
__global__ void k_scatter(const int* __restrict__ idx, int* __restrict__ cursor,
                          int* __restrict__ perm, int* __restrict__ inv_pos, int E) {
    int i = blockIdx.x * blockDim.x + threadIdx.x;
    if (i < E) {
        int q   = idx[i];
        int pos = atomicAdd(&cursor[q], 1);
        perm[pos]  = i;
        inv_pos[i] = pos;   // sequential write
    }
}

// ---------------- K_attn: per-segment softmax + weighted sum, pair-row ----
// block 256 = 4 waves; wave w owns segment q = blockIdx*4 + w.
// Lanes 0-31 = row a (float4/lane), lanes 32-63 = row b. 8 rows per inner step.
// ex written CONTIGUOUSLY to ex_sorted[start..start+cnt); k_rescale scatters later.
__global__ __launch_bounds__(256) void k_attn(const float* __restrict__ SV,
                                              const float* __restrict__ queries,
                                              const float* __restrict__ uvec,
                                              const float* __restrict__ s0ptr,
                                              const int* __restrict__ hist,
                                              const int* __restrict__ seg_start,
                                              const int* __restrict__ perm,
                                              float* __restrict__ zs_attn,   // [Q][128] in d_out
                                              float* __restrict__ ex_sorted, // [E] in ws
                                              float* __restrict__ invsum,    // [Q] in ws
                                              int Q, float scale) {
    const int wid  = threadIdx.x >> 6;
    const int lane = threadIdx.x & 63;
    const int q    = blockIdx.x * 4 + wid;
    if (q >= Q) return;
    const int half = lane >> 5;    // 0: row a, 1: row b
    const int col4 = lane & 31;    // columns col4*4 .. col4*4+3

    // zs fragment (both halves read the same addresses -> broadcast)
    const float4 zv = ((const float4*)(zs_attn + (size_t)q * DD))[col4];

    // cq = scale*(queries[q].u + s0), 64-lane butterfly
    float2 qv2 = ((const float2*)(queries + (size_t)q * DD))[lane];
    float2 uv2 = ((const float2*)uvec)[lane];
    float cd = fmaf(qv2.x, uv2.x, qv2.y * uv2.y);
    #pragma unroll
    for (int off = 1; off < 64; off <<= 1) cd += __shfl_xor(cd, off);
    const float cq = (cd + s0ptr[0]) * scale;

    const int cnt   = hist[q];
    const int start = seg_start[q];

    float4 acc = make_float4(0.f, 0.f, 0.f, 0.f);
    float ssum = 0.f;

    for (int base = 0; base < cnt; base += 64) {
        const int m = min(64, cnt - base);
        const int pe = perm[start + base + ((lane < m) ? lane : 0)];
        for (int i = 0; i < m; i += 8) {
            int   rr[4], valid[4];
            float4 sv[4];
            #pragma unroll
            for (int j = 0; j < 4; ++j) {
                rr[j]   = i + 2 * j + half;
                valid[j] = (rr[j] < m);
                int r   = valid[j] ? rr[j] : (m - 1);
                int e   = __shfl(pe, r);
                sv[j]   = ((const float4*)(SV + (size_t)e * DD))[col4];
            }
            float p[4];
            #pragma unroll
            for (int j = 0; j < 4; ++j)
                p[j] = fmaf(sv[j].x, zv.x, fmaf(sv[j].y, zv.y,
                        fmaf(sv[j].z, zv.z, sv[j].w * zv.w)));
            // 32-lane butterfly within each half (4 interleaved chains)
            #pragma unroll
            for (int off = 1; off < 32; off <<= 1) {
                p[0] += __shfl_xor(p[0], off);
                p[1] += __shfl_xor(p[1], off);
                p[2] += __shfl_xor(p[2], off);
                p[3] += __shfl_xor(p[3], off);
            }
            float ex[4];
            #pragma unroll
            for (int j = 0; j < 4; ++j) {
                ex[j] = valid[j] ? __expf(p[j] + cq) : 0.f;
                ssum += ex[j];
                acc.x = fmaf(ex[j], sv[j].x, acc.x);
                acc.y = fmaf(ex[j], sv[j].y, acc.y);
                acc.z = fmaf(ex[j], sv[j].z, acc.z);
                acc.w = fmaf(ex[j], sv[j].w, acc.w);
            }
            if (col4 == 0) {   // lanes 0 and 32 write their half's rows
                #pragma unroll
                for (int j = 0; j < 4; ++j)
                    if (valid[j]) ex_sorted[start + base + rr[j]] = ex[j];
            }
        }
    }

    // combine halves
    acc.x += __shfl_xor(acc.x, 32);
    acc.y += __shfl_xor(acc.y, 32);
    acc.z += __shfl_xor(acc.z, 32);
    acc.w += __shfl_xor(acc.w, 32);
    ssum  += __shfl_xor(ssum, 32);

    float4* arow = (float4*)(zs_attn + (size_t)q * DD);
    if (cnt == 0) {
        if (half == 0) arow[col4] = make_float4(0.f, 0.f, 0.f, 0.f);
    } else {
        const float inv = 1.f / ssum;
        if (half == 0)
            arow[col4] = make_float4(acc.x * inv, acc.y * inv, acc.z * inv, acc.w * inv);
        if (lane == 0) invsum[q] = inv;
    }
}

// ---------------- K_rescale: scores[e] = ex_sorted[inv_pos[e]] * invsum[idx[e]] ----
__global__ void k_rescale(const int* __restrict__ idx, const int* __restrict__ inv_pos,
                          const float* __restrict__ ex_sorted,
                          const float* __restrict__ invsum,
                          float* __restrict__ scores, int E) {
    int i = blockIdx.x * blockDim.x + threadIdx.x;
    if (i < E) scores[i] = ex_sorted[inv_pos[i]] * invsum[idx[i]];
}

extern "C" void kernel_launch(void* const* d_in, const int* in_sizes, int n_in,
                              void* d_out, int out_size, void* d_ws, size_t ws_size,
                              hipStream_t stream) {
    const float* SV      = (const float*)d_in[0];
    const int*   indices = (const int*)d_in[1];
    const float* queries = (const float*)d_in[2];
    const float* Wq      = (const float*)d_in[3];
    const float* bq      = (const float*)d_in[4];
    const float* Wk      = (const float*)d_in[5];
    const float* bk      = (const float*)d_in[6];

    const int E = in_sizes[1];
    const int Q = in_sizes[2] / DD;
    const float scale = 1.0f / sqrtf((float)DD);

    // d_out layout: scores [E] then attn [Q*128] (zs staged in attn region)
    float* scores  = (float*)d_out;
    float* zs_attn = (float*)d_out + E;

    // workspace layout (4-byte units)
    float* ws   = (float*)d_ws;
    float* M    = ws;                 // 16384
    float* tvec = ws + 16384;         // 128
    float* uvec = ws + 16512;         // 128
    float* s0   = ws + 16640;         // 1 (pad to 17024)
    int* hist      = (int*)ws + 17024;
    int* seg_start = hist + Q;
    int* cursor    = seg_start + Q;
    int* bsum      = cursor + Q;      // 256
    int* boff      = bsum + 256;      // 256
    int* done      = boff + 256;      // 1 (pad 64)
    int* perm      = done + 64;       // E
    int* inv_pos   = perm + E;        // E
    float* ex_sorted = (float*)(inv_pos + E);  // E
    float* invsum    = ex_sorted + E;          // Q

    const int NB = (Q + 255) / 256;   // scan blocks (Q=50k -> 196, <=256)
    const int GB = (Q + 63) / 64;     // gemm blocks
    const int HB = (E + 255) / 256;   // hist blocks

    hipLaunchKernelGGL(k_init, dim3(NB + 128), dim3(128), 0, stream,
                       Wq, bq, Wk, bk, M, tvec, uvec, s0, hist, done, Q, NB);
    hipLaunchKernelGGL(k_gemm_hist, dim3(GB + HB), dim3(256), 0, stream,
                       queries, M, tvec, zs_attn, Q, scale, indices, hist, E, GB);
    hipLaunchKernelGGL(k_scan12, dim3(NB), dim3(256), 0, stream,
                       hist, bsum, boff, done, Q, NB);
    hipLaunchKernelGGL(k_scan3, dim3(NB), dim3(256), 0, stream,
                       hist, boff, seg_start, cursor, Q);
    hipLaunchKernelGGL(k_scatter, dim3(HB), dim3(256), 0, stream,
                       indices, cursor, perm, inv_pos, E);
    hipLaunchKernelGGL(k_attn, dim3((Q + 3) / 4), dim3(256), 0, stream,
                       SV, queries, uvec, s0, hist, seg_start, perm,
                       zs_attn, ex_sorted, invsum, Q, scale);
    hipLaunchKernelGGL(k_rescale, dim3(HB), dim3(256), 0, stream,
                       indices, inv_pos, ex_sorted, invsum, scores, E);
}